// Round 1
// baseline (10304.057 us; speedup 1.0000x reference)
//
#include <hip/hip_runtime.h>
#include <cstdint>
#include <cstddef>

typedef float    float4v __attribute__((ext_vector_type(4)));
typedef _Float16 f16x4   __attribute__((ext_vector_type(4)));
typedef _Float16 f16x8   __attribute__((ext_vector_type(8)));
typedef unsigned long long u64;
typedef unsigned long long u64x2 __attribute__((ext_vector_type(2)));

#define DI __device__ __forceinline__

static const int Bsz = 64, Tlen = 2048, Hd = 128, G4 = 512;  // 4H=512
static const int Mrows = Bsz * Tlen;                          // 131072
static const int HSTR = 144;   // H row stride (f16): 0 bank conflicts, validated R7

DI float sigf_fast(float x) {
    float e = __builtin_amdgcn_exp2f(-1.442695041f * x);
    return __builtin_amdgcn_rcpf(1.f + e);
}
DI float tanhf_fast(float x) {
    float e = __builtin_amdgcn_exp2f(-2.885390082f * x);
    return 2.f * __builtin_amdgcn_rcpf(1.f + e) - 1.f;
}

// LDS-only barrier: no vmcnt drain (validated R5, -24%).
DI void lds_barrier() {
    asm volatile("s_waitcnt lgkmcnt(0)\n\ts_barrier" ::: "memory");
}

// Pin a 128-bit fragment in VGPRs: forbids rematerialization (per-step HBM
// reload of weights). Validated R8 (FETCH 66.6GB -> 66.6MB).
DI void pin(f16x8& v) {
    float4v t = __builtin_bit_cast(float4v, v);
    asm volatile("" : "+v"(t));
    v = __builtin_bit_cast(f16x8, t);
}

// load 8 consecutive f32, convert to f16x8
DI f16x8 cvt8(const float* p) {
    float4v u = *(const float4v*)p;
    float4v w = *(const float4v*)(p + 4);
    f16x8 o;
    o[0] = (_Float16)u[0]; o[1] = (_Float16)u[1]; o[2] = (_Float16)u[2]; o[3] = (_Float16)u[3];
    o[4] = (_Float16)w[0]; o[5] = (_Float16)w[1]; o[6] = (_Float16)w[2]; o[7] = (_Float16)w[3];
    return o;
}

// agent-scope (sc1) 16B load as two u64 atomics: bypasses stale per-XCD L2,
// reads at the device coherence point where the producer's sc1 stores land.
DI f16x8 ldy_agent(const _Float16* p) {
    u64* q = (u64*)p;
    u64x2 v;
    v.x = __hip_atomic_load(q,     __ATOMIC_RELAXED, __HIP_MEMORY_SCOPE_AGENT);
    v.y = __hip_atomic_load(q + 1, __ATOMIC_RELAXED, __HIP_MEMORY_SCOPE_AGENT);
    return __builtin_bit_cast(f16x8, v);
}

// ---------------------------------------------------------------------------
// GEMM: C[M,N] = A[M,128] @ Wsel^T (+bias). MFMA f32_16x16x32_f16.
// PERM: col n pulls W row ((n&3)*128 + (n>>2)) -> XP gate-interleaved (4j+q).
// Validated R4-R7.
// ---------------------------------------------------------------------------
template <bool A_F16, bool PERM, bool OUT_F32>
__global__ __launch_bounds__(256) void gemm_k128(
    const void* __restrict__ Av, const float* __restrict__ W,
    const float* __restrict__ bias, void* __restrict__ Cout, int M, int N)
{
    const int lane = threadIdx.x & 63, wave = threadIdx.x >> 6;
    const int m0 = blockIdx.y * 64 + wave * 16;
    const int n0 = blockIdx.x * 64;
    const int r15 = lane & 15, kg = lane >> 4;

    f16x8 a[4];
    if (A_F16) {
        const f16x8* Ar = (const f16x8*)((const _Float16*)Av + (size_t)(m0 + r15) * 128);
#pragma unroll
        for (int kt = 0; kt < 4; kt++) a[kt] = Ar[kt * 4 + kg];
    } else {
        const float* Ar = (const float*)Av + (size_t)(m0 + r15) * 128;
#pragma unroll
        for (int kt = 0; kt < 4; kt++) a[kt] = cvt8(Ar + kt * 32 + kg * 8);
    }

    f16x8 bfrg[4][4];
#pragma unroll
    for (int nt = 0; nt < 4; nt++) {
        int n = n0 + nt * 16 + r15;
        int wrow = PERM ? ((n & 3) * 128 + (n >> 2)) : n;
        const float* Wr = W + (size_t)wrow * 128;
#pragma unroll
        for (int kt = 0; kt < 4; kt++) bfrg[nt][kt] = cvt8(Wr + kt * 32 + kg * 8);
    }

    float4v acc[4] = {};
#pragma unroll
    for (int kt = 0; kt < 4; kt++)
#pragma unroll
        for (int nt = 0; nt < 4; nt++)
            acc[nt] = __builtin_amdgcn_mfma_f32_16x16x32_f16(a[kt], bfrg[nt][kt], acc[nt], 0, 0, 0);

#pragma unroll
    for (int nt = 0; nt < 4; nt++) {
        int n = n0 + nt * 16 + r15;
        float bv = bias ? bias[n] : 0.f;
#pragma unroll
        for (int r = 0; r < 4; r++) {
            int m = m0 + kg * 4 + r;
            float v = acc[nt][r] + bv;
            if (OUT_F32) ((float*)Cout)[(size_t)m * N + n] = v;
            else         ((_Float16*)Cout)[(size_t)m * N + n] = (_Float16)v;
        }
    }
}

// ---------------------------------------------------------------------------
// R9: fused two-layer wavefront pipeline. 32 WGs x 512 thr, one launch:
//   WG p<16   : producer = layer-0 recurrence (validated rec6 body) + publish
//               y(t) via agent(sc1) atomic u32 stores; progress counter
//               released every 8 steps with COUNTED s_waitcnt vmcnt(2/1):
//               only this step's {xp-load, y-store} may be outstanding ->
//               all waves' y(<=t-1) are ACKed at the device coherence point
//               before prog moves. Zero-stall release.
//   WG p>=16  : consumer = layer-1 recurrence, DUAL matvec: gates =
//               Wih@y0[t] (ih, from prefetched sc1 frags, issues before the
//               barrier-gated LDS read) + Whh@h (hh) accumulated into ONE
//               acc[4]. Replaces the inter-layer XP GEMM dispatch.
//   Poll latency hidden: an in-flight prog load per step, checked next step.
//   Producers never wait on consumers; 32 WGs <= 256 CUs -> co-resident.
// ---------------------------------------------------------------------------
template <bool P_HAS_XP, bool P_INIT, bool C_INIT, bool C_WRITE_Y>
__global__ __launch_bounds__(512, 1) void lstm_fused2(
    // producer (first layer of this phase)
    const float* __restrict__ Up, const float* __restrict__ bip, const float* __restrict__ bhp,
    const _Float16* __restrict__ XPp,
    const float* __restrict__ php, const float* __restrict__ pcp,
    float* __restrict__ fhp, float* __restrict__ fcp,
    // consumer (second layer of this phase)
    const float* __restrict__ Wc, const float* __restrict__ Uc,
    const float* __restrict__ bic, const float* __restrict__ bhc,
    const float* __restrict__ phc, const float* __restrict__ pcc,
    float* __restrict__ fhc, float* __restrict__ fcc,
    _Float16* __restrict__ PB,          // publish buffer [B,T,128] f16
    _Float16* __restrict__ Yc,          // consumer plain y out (or null)
    unsigned int* __restrict__ prog, int T)
{
    const int tid  = threadIdx.x;
    const int lane = tid & 63, w = tid >> 6;
    const int col  = lane & 15, quad = lane >> 4;
    const int b    = col & 3, s = col >> 2;
    const bool isC = blockIdx.x >= 16;
    const int p    = blockIdx.x & 15;
    const int bglob = p * 4 + b;
    const int j    = w * 16 + s * 4 + quad;

    __shared__ alignas(16) _Float16 Hl[2 * 4 * HSTR];

    unsigned int* pr = prog + p;

    if (!isC) {
        // ================= producer =================
        f16x8 af[4][4];
#pragma unroll
        for (int mt = 0; mt < 4; mt++) {
            int urow = (col & 3) * 128 + (w * 16 + mt * 4 + (col >> 2));
            const float* ur = Up + (size_t)urow * 128;
#pragma unroll
            for (int kc = 0; kc < 4; kc++) af[mt][kc] = cvt8(ur + kc * 32 + quad * 8);
        }
#pragma unroll
        for (int mt = 0; mt < 4; mt++)
#pragma unroll
            for (int kc = 0; kc < 4; kc++) pin(af[mt][kc]);

        float bq[4];
#pragma unroll
        for (int q = 0; q < 4; q++) bq[q] = bip[q * 128 + j] + bhp[q * 128 + j];

        float c = 0.f, hv = 0.f;
        if (P_INIT) {
            c  = pcp[(size_t)bglob * 128 + j];
            hv = php[(size_t)bglob * 128 + j];
        }
        Hl[b * HSTR + j] = (_Float16)hv;
        __syncthreads();

        const _Float16* xb = P_HAS_XP ? XPp + ((size_t)bglob * T) * 512 + 4 * j : nullptr;
        f16x4 xp = {};
        if (P_HAS_XP) xp = *(const f16x4*)xb;

        int cur = 0;
        for (int t = 0; t < T; t++) {
            f16x4 xpn = {};
            if (P_HAS_XP && (t + 1 < T)) xpn = *(const f16x4*)(xb + (size_t)(t + 1) * 512);

            const _Float16* Hc = Hl + cur * (4 * HSTR);
            f16x8 bf[4];
#pragma unroll
            for (int kc = 0; kc < 4; kc++)
                bf[kc] = *(const f16x8*)(Hc + b * HSTR + kc * 32 + quad * 8);

            float4v acc[4] = {};
#pragma unroll
            for (int kc = 0; kc < 4; kc++)
#pragma unroll
                for (int mt = 0; mt < 4; mt++)
                    acc[mt] = __builtin_amdgcn_mfma_f32_16x16x32_f16(af[mt][kc], bf[kc], acc[mt], 0, 0, 0);

            float4v t0 = (s & 1) ? acc[1] : acc[0];
            float4v t1 = (s & 1) ? acc[3] : acc[2];
            float4v g  = (s & 2) ? t1 : t0;

            float g0 = g[0] + bq[0], g1 = g[1] + bq[1], g2 = g[2] + bq[2], g3 = g[3] + bq[3];
            if (P_HAS_XP) { g0 += (float)xp[0]; g1 += (float)xp[1]; g2 += (float)xp[2]; g3 += (float)xp[3]; }
            float iv = sigf_fast(g0), fv = sigf_fast(g1);
            float gv = tanhf_fast(g2), ov = sigf_fast(g3);
            c  = fv * c + iv * gv;
            hv = ov * tanhf_fast(c);

            _Float16 hf = (_Float16)hv;
            Hl[(cur ^ 1) * (4 * HSTR) + b * HSTR + j] = hf;

            // publish y(t): pack (j, j+1) pairs, agent-scope u32 store
            unsigned short hs = __builtin_bit_cast(unsigned short, hf);
            unsigned int ov16 = (unsigned int)__shfl_down((int)hs, 16);   // j+1 lives at lane+16
            if (!(quad & 1)) {
                unsigned int pk = (unsigned int)hs | (ov16 << 16);
                __hip_atomic_store((unsigned int*)(PB + ((size_t)bglob * T + t) * 128 + j), pk,
                                   __ATOMIC_RELAXED, __HIP_MEMORY_SCOPE_AGENT);
            }

            if ((t & 7) == 7) {
                // counted release: allow only this step's {xp-load, y-store}
                // (no xp: just the y-store) outstanding -> all y(<=t-1) ACKed.
                if constexpr (P_HAS_XP) asm volatile("s_waitcnt vmcnt(2)" ::: "memory");
                else                    asm volatile("s_waitcnt vmcnt(1)" ::: "memory");
                lds_barrier();
                if (tid == 0)
                    __hip_atomic_store(pr, (unsigned int)t,  // steps 0..t-1 ready
                                       __ATOMIC_RELAXED, __HIP_MEMORY_SCOPE_AGENT);
            } else {
                lds_barrier();
            }

            xp = xpn;
            cur ^= 1;
        }

        asm volatile("s_waitcnt vmcnt(0)" ::: "memory");
        __syncthreads();
        if (tid == 0)
            __hip_atomic_store(pr, (unsigned int)T, __ATOMIC_RELAXED, __HIP_MEMORY_SCOPE_AGENT);

        fhp[(size_t)bglob * 128 + j] = hv;
        fcp[(size_t)bglob * 128 + j] = c;
    } else {
        // ================= consumer (dual matvec) =================
        f16x8 afI[4][4], afH[4][4];
#pragma unroll
        for (int mt = 0; mt < 4; mt++) {
            int urow = (col & 3) * 128 + (w * 16 + mt * 4 + (col >> 2));
            const float* wr = Wc + (size_t)urow * 128;
            const float* ur = Uc + (size_t)urow * 128;
#pragma unroll
            for (int kc = 0; kc < 4; kc++) {
                afI[mt][kc] = cvt8(wr + kc * 32 + quad * 8);
                afH[mt][kc] = cvt8(ur + kc * 32 + quad * 8);
            }
        }
#pragma unroll
        for (int mt = 0; mt < 4; mt++)
#pragma unroll
            for (int kc = 0; kc < 4; kc++) { pin(afI[mt][kc]); pin(afH[mt][kc]); }

        float bq[4];
#pragma unroll
        for (int q = 0; q < 4; q++) bq[q] = bic[q * 128 + j] + bhc[q * 128 + j];

        float c = 0.f, hv = 0.f;
        if (C_INIT) {
            c  = pcc[(size_t)bglob * 128 + j];
            hv = phc[(size_t)bglob * 128 + j];
        }
        Hl[b * HSTR + j] = (_Float16)hv;
        __syncthreads();

        const _Float16* yb = PB + ((size_t)bglob * T) * 128;

        // wait for first publish (producer needs ~8 steps)
        unsigned int pseen = 0;
        do {
            pseen = __hip_atomic_load(pr, __ATOMIC_RELAXED, __HIP_MEMORY_SCOPE_AGENT);
            if (pseen < 1u) __builtin_amdgcn_s_sleep(8);
        } while (pseen < 1u);
        unsigned int pf = pseen;  // in-flight progress sample, checked next step

        f16x8 ycur[4], ynext[4];
#pragma unroll
        for (int kc = 0; kc < 4; kc++) ycur[kc] = ldy_agent(yb + kc * 32 + quad * 8);

        int cur = 0;
        for (int t = 0; t < T; t++) {
            if (t + 1 < T) {
                unsigned int need = (unsigned int)(t + 2);
                if (pf > pseen) pseen = pf;             // adopt last step's sample (free)
                pf = __hip_atomic_load(pr, __ATOMIC_RELAXED, __HIP_MEMORY_SCOPE_AGENT);
                while (pseen < need) {                  // true spin: rare, self-regulating
                    __builtin_amdgcn_s_sleep(4);
                    pseen = __hip_atomic_load(pr, __ATOMIC_RELAXED, __HIP_MEMORY_SCOPE_AGENT);
                }
                const _Float16* yr = yb + (size_t)(t + 1) * 128;
#pragma unroll
                for (int kc = 0; kc < 4; kc++) ynext[kc] = ldy_agent(yr + kc * 32 + quad * 8);
            }

            // ih part first: depends only on prefetched ycur, fills the
            // barrier/LDS-read latency before the hh chain.
            float4v acc[4] = {};
#pragma unroll
            for (int kc = 0; kc < 4; kc++)
#pragma unroll
                for (int mt = 0; mt < 4; mt++)
                    acc[mt] = __builtin_amdgcn_mfma_f32_16x16x32_f16(afI[mt][kc], ycur[kc], acc[mt], 0, 0, 0);

            const _Float16* Hc = Hl + cur * (4 * HSTR);
            f16x8 bf[4];
#pragma unroll
            for (int kc = 0; kc < 4; kc++)
                bf[kc] = *(const f16x8*)(Hc + b * HSTR + kc * 32 + quad * 8);
#pragma unroll
            for (int kc = 0; kc < 4; kc++)
#pragma unroll
                for (int mt = 0; mt < 4; mt++)
                    acc[mt] = __builtin_amdgcn_mfma_f32_16x16x32_f16(afH[mt][kc], bf[kc], acc[mt], 0, 0, 0);

            float4v t0 = (s & 1) ? acc[1] : acc[0];
            float4v t1 = (s & 1) ? acc[3] : acc[2];
            float4v g  = (s & 2) ? t1 : t0;

            float g0 = g[0] + bq[0], g1 = g[1] + bq[1], g2 = g[2] + bq[2], g3 = g[3] + bq[3];
            float iv = sigf_fast(g0), fv = sigf_fast(g1);
            float gv = tanhf_fast(g2), ov = sigf_fast(g3);
            c  = fv * c + iv * gv;
            hv = ov * tanhf_fast(c);

            Hl[(cur ^ 1) * (4 * HSTR) + b * HSTR + j] = (_Float16)hv;
            if (C_WRITE_Y)
                Yc[((size_t)bglob * T + t) * 128 + j] = (_Float16)hv;
            lds_barrier();

#pragma unroll
            for (int kc = 0; kc < 4; kc++) ycur[kc] = ynext[kc];
            cur ^= 1;
        }

        fhc[(size_t)bglob * 128 + j] = hv;
        fcc[(size_t)bglob * 128 + j] = c;
    }
}

// ---------------------------------------------------------------------------
// Host side: memset + 4 stream-ordered launches (was 8).
//   ws: XP f16 [131072,512] perm (128MB) | Y f16 [131072,128] (32MB) | finals
//   prog counters: first 128B of d_out (dead scratch until final GEMM).
// ---------------------------------------------------------------------------
extern "C" void kernel_launch(void* const* d_in, const int* in_sizes, int n_in,
                              void* d_out, int out_size, void* d_ws, size_t ws_size,
                              hipStream_t stream)
{
    const float* x    = (const float*)d_in[0];
    const float* eW0  = (const float*)d_in[1];
    const float* eU0  = (const float*)d_in[2];
    const float* eb0i = (const float*)d_in[3];
    const float* eb0h = (const float*)d_in[4];
    const float* eW1  = (const float*)d_in[5];
    const float* eU1  = (const float*)d_in[6];
    const float* eb1i = (const float*)d_in[7];
    const float* eb1h = (const float*)d_in[8];
    const float* dU0  = (const float*)d_in[10];
    const float* db0i = (const float*)d_in[11];
    const float* db0h = (const float*)d_in[12];
    const float* dW1  = (const float*)d_in[13];
    const float* dU1  = (const float*)d_in[14];
    const float* db1i = (const float*)d_in[15];
    const float* db1h = (const float*)d_in[16];
    const float* oW   = (const float*)d_in[17];
    const float* ob   = (const float*)d_in[18];

    char* ws = (char*)d_ws;
    _Float16* XP  = (_Float16*)ws;                              // 134217728 B
    _Float16* Y   = (_Float16*)(ws + 134217728);                //  33554432 B
    float*    fh0 = (float*)(ws + 167772160);
    float*    fc0 = fh0 + Bsz * Hd;
    float*    fh1 = fc0 + Bsz * Hd;
    float*    fc1 = fh1 + Bsz * Hd;

    unsigned int* progA = (unsigned int*)d_out;   // 16 u32
    unsigned int* progB = progA + 16;             // 16 u32

    dim3 blk(256);
    dim3 gXP(G4 / 64, Mrows / 64);    // (8, 2048)
    dim3 gOut(Hd / 64, Mrows / 64);   // (2, 2048)

    // zero progress counters (graph-safe, re-zeroed every replay)
    hipMemsetAsync(d_out, 0, 128, stream);

    // 1) XP = x @ enc_Wih0^T (permuted, f16)
    gemm_k128<false, true, false><<<gXP, blk, 0, stream>>>((const void*)x, eW0, (const float*)nullptr, (void*)XP, Mrows, G4);

    // 2) encoder phase: encL0 (producer) || encL1 (consumer, dual matvec)
    lstm_fused2<true, false, false, false><<<dim3(32), dim3(512), 0, stream>>>(
        eU0, eb0i, eb0h, XP, (const float*)nullptr, (const float*)nullptr, fh0, fc0,
        eW1, eU1, eb1i, eb1h, (const float*)nullptr, (const float*)nullptr, fh1, fc1,
        Y, (_Float16*)nullptr, progA, Tlen);

    // 3) decoder phase: decL0 (producer, zero input, init enc finals) ||
    //    decL1 (consumer, init enc finals, writes final y to Y)
    lstm_fused2<false, true, true, true><<<dim3(32), dim3(512), 0, stream>>>(
        dU0, db0i, db0h, (const _Float16*)nullptr, fh0, fc0, fh0, fc0,
        dW1, dU1, db1i, db1h, fh1, fc1, fh1, fc1,
        XP /*publish scratch*/, Y, progB, Tlen);

    // 4) out = d1 @ out_W^T + out_b (f32 -> d_out, overwrites prog scratch)
    gemm_k128<true, false, true><<<gOut, blk, 0, stream>>>((const void*)Y, oW, ob, d_out, Mrows, Hd);
}

// Round 2
// 3797.301 us; speedup vs baseline: 2.7135x; 2.7135x over previous
//
#include <hip/hip_runtime.h>
#include <cstdint>
#include <cstddef>

typedef float    float4v __attribute__((ext_vector_type(4)));
typedef _Float16 f16x4   __attribute__((ext_vector_type(4)));
typedef _Float16 f16x8   __attribute__((ext_vector_type(8)));
typedef unsigned long long u64;

#define DI __device__ __forceinline__

static const int Bsz = 64, Tlen = 2048, Hd = 128, G4 = 512;  // 4H=512
static const int Mrows = Bsz * Tlen;                          // 131072
static const int HSTR = 144;   // H row stride (f16): 0 bank conflicts, validated R7

DI float sigf_fast(float x) {
    float e = __builtin_amdgcn_exp2f(-1.442695041f * x);
    return __builtin_amdgcn_rcpf(1.f + e);
}
DI float tanhf_fast(float x) {
    float e = __builtin_amdgcn_exp2f(-2.885390082f * x);
    return 2.f * __builtin_amdgcn_rcpf(1.f + e) - 1.f;
}

// LDS-only barrier: no vmcnt drain (validated R5, -24%).
DI void lds_barrier() {
    asm volatile("s_waitcnt lgkmcnt(0)\n\ts_barrier" ::: "memory");
}

// Pin a 128-bit fragment in VGPRs: forbids rematerialization (per-step HBM
// reload of weights). Validated R8 (FETCH 66.6GB -> 66.6MB).
DI void pin(f16x8& v) {
    float4v t = __builtin_bit_cast(float4v, v);
    asm volatile("" : "+v"(t));
    v = __builtin_bit_cast(f16x8, t);
}

// load 8 consecutive f32, convert to f16x8
DI f16x8 cvt8(const float* p) {
    float4v u = *(const float4v*)p;
    float4v w = *(const float4v*)(p + 4);
    f16x8 o;
    o[0] = (_Float16)u[0]; o[1] = (_Float16)u[1]; o[2] = (_Float16)u[2]; o[3] = (_Float16)u[3];
    o[4] = (_Float16)w[0]; o[5] = (_Float16)w[1]; o[6] = (_Float16)w[2]; o[7] = (_Float16)w[3];
    return o;
}

// ---------------------------------------------------------------------------
// GEMM: C[M,N] = A[M,128] @ Wsel^T (+bias). MFMA f32_16x16x32_f16.
// PERM: col n pulls W row ((n&3)*128 + (n>>2)) -> XP gate-interleaved (4j+q).
// Validated R4-R7.
// ---------------------------------------------------------------------------
template <bool A_F16, bool PERM, bool OUT_F32>
__global__ __launch_bounds__(256) void gemm_k128(
    const void* __restrict__ Av, const float* __restrict__ W,
    const float* __restrict__ bias, void* __restrict__ Cout, int M, int N)
{
    const int lane = threadIdx.x & 63, wave = threadIdx.x >> 6;
    const int m0 = blockIdx.y * 64 + wave * 16;
    const int n0 = blockIdx.x * 64;
    const int r15 = lane & 15, kg = lane >> 4;

    f16x8 a[4];
    if (A_F16) {
        const f16x8* Ar = (const f16x8*)((const _Float16*)Av + (size_t)(m0 + r15) * 128);
#pragma unroll
        for (int kt = 0; kt < 4; kt++) a[kt] = Ar[kt * 4 + kg];
    } else {
        const float* Ar = (const float*)Av + (size_t)(m0 + r15) * 128;
#pragma unroll
        for (int kt = 0; kt < 4; kt++) a[kt] = cvt8(Ar + kt * 32 + kg * 8);
    }

    f16x8 bfrg[4][4];
#pragma unroll
    for (int nt = 0; nt < 4; nt++) {
        int n = n0 + nt * 16 + r15;
        int wrow = PERM ? ((n & 3) * 128 + (n >> 2)) : n;
        const float* Wr = W + (size_t)wrow * 128;
#pragma unroll
        for (int kt = 0; kt < 4; kt++) bfrg[nt][kt] = cvt8(Wr + kt * 32 + kg * 8);
    }

    float4v acc[4] = {};
#pragma unroll
    for (int kt = 0; kt < 4; kt++)
#pragma unroll
        for (int nt = 0; nt < 4; nt++)
            acc[nt] = __builtin_amdgcn_mfma_f32_16x16x32_f16(a[kt], bfrg[nt][kt], acc[nt], 0, 0, 0);

#pragma unroll
    for (int nt = 0; nt < 4; nt++) {
        int n = n0 + nt * 16 + r15;
        float bv = bias ? bias[n] : 0.f;
#pragma unroll
        for (int r = 0; r < 4; r++) {
            int m = m0 + kg * 4 + r;
            float v = acc[nt][r] + bv;
            if (OUT_F32) ((float*)Cout)[(size_t)m * N + n] = v;
            else         ((_Float16*)Cout)[(size_t)m * N + n] = (_Float16)v;
        }
    }
}

// ---------------------------------------------------------------------------
// R10: fused wavefront pipeline, storm-free handoff.
// R9 post-mortem: per-step ALL-thread agent-atomic polling (512 same-addr
// loads/WG/step) + 32-way duplicated same-addr y-loads serialized at the
// coherence point (~2.4us/step -> 4950us). Fix:
//   - ONE poller thread (tid 511) spins on prog during step t to guarantee
//     y(t+2) for step t+1's loaders; guarantee handed off by the existing
//     end-of-step lds_barrier. 512x less poll traffic.
//   - y(t+1) staged into double-buffered LDS by 128 loader threads, each
//     loading one UNIQUE u64 (zero same-addr duplication); consumers read
//     MFMA fragments from LDS with the validated conflict-free HSTR pattern.
//   - prog counters padded to 64B stride (no single-line hammering).
//   - consumer: separate accI/accH chains (2x 4-deep instead of 1x 8-deep).
// Producer branch unchanged from R9 (counted-vmcnt release every 8 steps).
// ---------------------------------------------------------------------------
template <bool P_HAS_XP, bool P_INIT, bool C_INIT, bool C_WRITE_Y>
__global__ __launch_bounds__(512, 1) void lstm_fused2(
    const float* __restrict__ Up, const float* __restrict__ bip, const float* __restrict__ bhp,
    const _Float16* __restrict__ XPp,
    const float* __restrict__ php, const float* __restrict__ pcp,
    float* __restrict__ fhp, float* __restrict__ fcp,
    const float* __restrict__ Wc, const float* __restrict__ Uc,
    const float* __restrict__ bic, const float* __restrict__ bhc,
    const float* __restrict__ phc, const float* __restrict__ pcc,
    float* __restrict__ fhc, float* __restrict__ fcc,
    _Float16* __restrict__ PB,          // publish buffer [B,T,128] f16
    _Float16* __restrict__ Yc,          // consumer plain y out (or null)
    unsigned int* __restrict__ prog, int T)
{
    const int tid  = threadIdx.x;
    const int lane = tid & 63, w = tid >> 6;
    const int col  = lane & 15, quad = lane >> 4;
    const int b    = col & 3, s = col >> 2;
    const bool isC = blockIdx.x >= 16;
    const int p    = blockIdx.x & 15;
    const int bglob = p * 4 + b;
    const int j    = w * 16 + s * 4 + quad;

    __shared__ alignas(16) _Float16 Hl[2 * 4 * HSTR];
    __shared__ alignas(16) _Float16 Yl[2][4 * HSTR];   // staged y(t), consumer only

    unsigned int* pr = prog + p * 16;   // 64B stride: no shared-line hammering

    if (!isC) {
        // ================= producer (unchanged from R9) =================
        f16x8 af[4][4];
#pragma unroll
        for (int mt = 0; mt < 4; mt++) {
            int urow = (col & 3) * 128 + (w * 16 + mt * 4 + (col >> 2));
            const float* ur = Up + (size_t)urow * 128;
#pragma unroll
            for (int kc = 0; kc < 4; kc++) af[mt][kc] = cvt8(ur + kc * 32 + quad * 8);
        }
#pragma unroll
        for (int mt = 0; mt < 4; mt++)
#pragma unroll
            for (int kc = 0; kc < 4; kc++) pin(af[mt][kc]);

        float bq[4];
#pragma unroll
        for (int q = 0; q < 4; q++) bq[q] = bip[q * 128 + j] + bhp[q * 128 + j];

        float c = 0.f, hv = 0.f;
        if (P_INIT) {
            c  = pcp[(size_t)bglob * 128 + j];
            hv = php[(size_t)bglob * 128 + j];
        }
        Hl[b * HSTR + j] = (_Float16)hv;
        __syncthreads();

        const _Float16* xb = P_HAS_XP ? XPp + ((size_t)bglob * T) * 512 + 4 * j : nullptr;
        f16x4 xp = {};
        if (P_HAS_XP) xp = *(const f16x4*)xb;

        int cur = 0;
        for (int t = 0; t < T; t++) {
            f16x4 xpn = {};
            if (P_HAS_XP && (t + 1 < T)) xpn = *(const f16x4*)(xb + (size_t)(t + 1) * 512);

            const _Float16* Hc = Hl + cur * (4 * HSTR);
            f16x8 bf[4];
#pragma unroll
            for (int kc = 0; kc < 4; kc++)
                bf[kc] = *(const f16x8*)(Hc + b * HSTR + kc * 32 + quad * 8);

            float4v acc[4] = {};
#pragma unroll
            for (int kc = 0; kc < 4; kc++)
#pragma unroll
                for (int mt = 0; mt < 4; mt++)
                    acc[mt] = __builtin_amdgcn_mfma_f32_16x16x32_f16(af[mt][kc], bf[kc], acc[mt], 0, 0, 0);

            float4v t0 = (s & 1) ? acc[1] : acc[0];
            float4v t1 = (s & 1) ? acc[3] : acc[2];
            float4v g  = (s & 2) ? t1 : t0;

            float g0 = g[0] + bq[0], g1 = g[1] + bq[1], g2 = g[2] + bq[2], g3 = g[3] + bq[3];
            if (P_HAS_XP) { g0 += (float)xp[0]; g1 += (float)xp[1]; g2 += (float)xp[2]; g3 += (float)xp[3]; }
            float iv = sigf_fast(g0), fv = sigf_fast(g1);
            float gv = tanhf_fast(g2), ov = sigf_fast(g3);
            c  = fv * c + iv * gv;
            hv = ov * tanhf_fast(c);

            _Float16 hf = (_Float16)hv;
            Hl[(cur ^ 1) * (4 * HSTR) + b * HSTR + j] = hf;

            // publish y(t): pack (j, j+1) pairs, agent-scope u32 store
            unsigned short hs = __builtin_bit_cast(unsigned short, hf);
            unsigned int ov16 = (unsigned int)__shfl_down((int)hs, 16);   // j+1 at lane+16
            if (!(quad & 1)) {
                unsigned int pk = (unsigned int)hs | (ov16 << 16);
                __hip_atomic_store((unsigned int*)(PB + ((size_t)bglob * T + t) * 128 + j), pk,
                                   __ATOMIC_RELAXED, __HIP_MEMORY_SCOPE_AGENT);
            }

            if ((t & 7) == 7) {
                // counted release: only this step's {xp-load, y-store} may
                // remain outstanding -> all y(<=t-1) ACKed at coherence pt.
                if constexpr (P_HAS_XP) asm volatile("s_waitcnt vmcnt(2)" ::: "memory");
                else                    asm volatile("s_waitcnt vmcnt(1)" ::: "memory");
                lds_barrier();
                if (tid == 0)
                    __hip_atomic_store(pr, (unsigned int)t,   // steps 0..t-1 ready
                                       __ATOMIC_RELAXED, __HIP_MEMORY_SCOPE_AGENT);
            } else {
                lds_barrier();
            }

            xp = xpn;
            cur ^= 1;
        }

        asm volatile("s_waitcnt vmcnt(0)" ::: "memory");
        __syncthreads();
        if (tid == 0)
            __hip_atomic_store(pr, (unsigned int)T, __ATOMIC_RELAXED, __HIP_MEMORY_SCOPE_AGENT);

        fhp[(size_t)bglob * 128 + j] = hv;
        fcp[(size_t)bglob * 128 + j] = c;
    } else {
        // ================= consumer (LDS-staged y, single poller) =========
        f16x8 afI[4][4], afH[4][4];
#pragma unroll
        for (int mt = 0; mt < 4; mt++) {
            int urow = (col & 3) * 128 + (w * 16 + mt * 4 + (col >> 2));
            const float* wr = Wc + (size_t)urow * 128;
            const float* ur = Uc + (size_t)urow * 128;
#pragma unroll
            for (int kc = 0; kc < 4; kc++) {
                afI[mt][kc] = cvt8(wr + kc * 32 + quad * 8);
                afH[mt][kc] = cvt8(ur + kc * 32 + quad * 8);
            }
        }
#pragma unroll
        for (int mt = 0; mt < 4; mt++)
#pragma unroll
            for (int kc = 0; kc < 4; kc++) { pin(afI[mt][kc]); pin(afH[mt][kc]); }

        float bq[4];
#pragma unroll
        for (int q = 0; q < 4; q++) bq[q] = bic[q * 128 + j] + bhc[q * 128 + j];

        float c = 0.f, hv = 0.f;
        if (C_INIT) {
            c  = pcc[(size_t)bglob * 128 + j];
            hv = phc[(size_t)bglob * 128 + j];
        }
        Hl[b * HSTR + j] = (_Float16)hv;

        // loader mapping: tid<128 -> one unique u64 of y-row (4 batches x 256B)
        const bool isLoader = (tid < 128);
        const int lb = (tid >> 5) & 3, lc = tid & 31;
        const _Float16* lyb = PB + ((size_t)(p * 4 + lb) * T) * 128 + lc * 4;
        char* lws = (char*)&Yl[0][0];
        const int lo = lb * (HSTR * 2) + lc * 8;   // byte offset in Yl row-block

        // pre-loop: poller guarantees y(0),y(1) readable (prog >= 2)
        unsigned int psn = 0;
        if (tid == 511) {
            unsigned int need0 = (T < 2) ? (unsigned int)T : 2u;
            psn = __hip_atomic_load(pr, __ATOMIC_RELAXED, __HIP_MEMORY_SCOPE_AGENT);
            while (psn < need0) {
                __builtin_amdgcn_s_sleep(8);
                psn = __hip_atomic_load(pr, __ATOMIC_RELAXED, __HIP_MEMORY_SCOPE_AGENT);
            }
        }
        __syncthreads();
        if (isLoader && T > 0) {
            u64 v0 = __hip_atomic_load((const u64*)lyb, __ATOMIC_RELAXED, __HIP_MEMORY_SCOPE_AGENT);
            *(u64*)(lws + lo) = v0;   // Yl[0]
        }
        lds_barrier();

        int cur = 0;
        for (int t = 0; t < T; t++) {
            // issue y(t+1) loads EARLY: latency hides under the MFMA phase
            const bool doload = isLoader && (t + 1 < T);
            u64 yv = 0;
            if (doload)
                yv = __hip_atomic_load((const u64*)(lyb + (size_t)(t + 1) * 128),
                                       __ATOMIC_RELAXED, __HIP_MEMORY_SCOPE_AGENT);

            const _Float16* Hc = Hl + cur * (4 * HSTR);
            const _Float16* Yb = &Yl[cur][0];
            f16x8 yf[4], bf[4];
#pragma unroll
            for (int kc = 0; kc < 4; kc++) {
                yf[kc] = *(const f16x8*)(Yb + b * HSTR + kc * 32 + quad * 8);
                bf[kc] = *(const f16x8*)(Hc + b * HSTR + kc * 32 + quad * 8);
            }

            // two independent 4-deep chains (ih and hh)
            float4v accI[4] = {}, accH[4] = {};
#pragma unroll
            for (int kc = 0; kc < 4; kc++)
#pragma unroll
                for (int mt = 0; mt < 4; mt++) {
                    accI[mt] = __builtin_amdgcn_mfma_f32_16x16x32_f16(afI[mt][kc], yf[kc], accI[mt], 0, 0, 0);
                    accH[mt] = __builtin_amdgcn_mfma_f32_16x16x32_f16(afH[mt][kc], bf[kc], accH[mt], 0, 0, 0);
                }

            float4v i0 = (s & 1) ? accI[1] : accI[0];
            float4v i1 = (s & 1) ? accI[3] : accI[2];
            float4v gI = (s & 2) ? i1 : i0;
            float4v h0 = (s & 1) ? accH[1] : accH[0];
            float4v h1 = (s & 1) ? accH[3] : accH[2];
            float4v gH = (s & 2) ? h1 : h0;

            float g0 = gI[0] + gH[0] + bq[0], g1 = gI[1] + gH[1] + bq[1];
            float g2 = gI[2] + gH[2] + bq[2], g3 = gI[3] + gH[3] + bq[3];
            float iv = sigf_fast(g0), fv = sigf_fast(g1);
            float gv = tanhf_fast(g2), ov = sigf_fast(g3);
            c  = fv * c + iv * gv;
            hv = ov * tanhf_fast(c);

            Hl[(cur ^ 1) * (4 * HSTR) + b * HSTR + j] = (_Float16)hv;
            if (C_WRITE_Y)
                Yc[((size_t)bglob * T + t) * 128 + j] = (_Float16)hv;

            // stage y(t+1) into the other buffer (compiler inserts the vmcnt
            // wait here -- load had the whole compute phase to complete)
            if (doload)
                *(u64*)(lws + (cur ^ 1) * (4 * HSTR * 2) + lo) = yv;

            // poller: during step t, guarantee y(t+2) for step t+1's loaders.
            // Handoff is the barrier below; nobody else ever touches prog.
            if (tid == 511 && (t + 2 < T)) {
                unsigned int need = (unsigned int)(t + 3);
                if (psn < need) {
                    psn = __hip_atomic_load(pr, __ATOMIC_RELAXED, __HIP_MEMORY_SCOPE_AGENT);
                    while (psn < need) {
                        __builtin_amdgcn_s_sleep(2);
                        psn = __hip_atomic_load(pr, __ATOMIC_RELAXED, __HIP_MEMORY_SCOPE_AGENT);
                    }
                }
            }
            lds_barrier();
            cur ^= 1;
        }

        fhc[(size_t)bglob * 128 + j] = hv;
        fcc[(size_t)bglob * 128 + j] = c;
    }
}

// ---------------------------------------------------------------------------
// Host side: memset + 4 stream-ordered launches.
//   ws: XP f16 [131072,512] perm (128MB) | Y f16 [131072,128] (32MB) | finals
//   prog counters: first 2KB of d_out (64B stride x 16 x 2 phases), dead
//   scratch until the final GEMM overwrites it.
// ---------------------------------------------------------------------------
extern "C" void kernel_launch(void* const* d_in, const int* in_sizes, int n_in,
                              void* d_out, int out_size, void* d_ws, size_t ws_size,
                              hipStream_t stream)
{
    const float* x    = (const float*)d_in[0];
    const float* eW0  = (const float*)d_in[1];
    const float* eU0  = (const float*)d_in[2];
    const float* eb0i = (const float*)d_in[3];
    const float* eb0h = (const float*)d_in[4];
    const float* eW1  = (const float*)d_in[5];
    const float* eU1  = (const float*)d_in[6];
    const float* eb1i = (const float*)d_in[7];
    const float* eb1h = (const float*)d_in[8];
    const float* dU0  = (const float*)d_in[10];
    const float* db0i = (const float*)d_in[11];
    const float* db0h = (const float*)d_in[12];
    const float* dW1  = (const float*)d_in[13];
    const float* dU1  = (const float*)d_in[14];
    const float* db1i = (const float*)d_in[15];
    const float* db1h = (const float*)d_in[16];
    const float* oW   = (const float*)d_in[17];
    const float* ob   = (const float*)d_in[18];

    char* ws = (char*)d_ws;
    _Float16* XP  = (_Float16*)ws;                              // 134217728 B
    _Float16* Y   = (_Float16*)(ws + 134217728);                //  33554432 B
    float*    fh0 = (float*)(ws + 167772160);
    float*    fc0 = fh0 + Bsz * Hd;
    float*    fh1 = fc0 + Bsz * Hd;
    float*    fc1 = fh1 + Bsz * Hd;

    unsigned int* progA = (unsigned int*)d_out;     // 16 x 64B
    unsigned int* progB = progA + 16 * 16;          // 16 x 64B

    dim3 blk(256);
    dim3 gXP(G4 / 64, Mrows / 64);    // (8, 2048)
    dim3 gOut(Hd / 64, Mrows / 64);   // (2, 2048)

    // zero progress counters (graph-safe, re-zeroed every replay)
    hipMemsetAsync(d_out, 0, 2048, stream);

    // 1) XP = x @ enc_Wih0^T (permuted, f16)
    gemm_k128<false, true, false><<<gXP, blk, 0, stream>>>((const void*)x, eW0, (const float*)nullptr, (void*)XP, Mrows, G4);

    // 2) encoder phase: encL0 (producer) || encL1 (consumer, dual matvec)
    lstm_fused2<true, false, false, false><<<dim3(32), dim3(512), 0, stream>>>(
        eU0, eb0i, eb0h, XP, (const float*)nullptr, (const float*)nullptr, fh0, fc0,
        eW1, eU1, eb1i, eb1h, (const float*)nullptr, (const float*)nullptr, fh1, fc1,
        Y, (_Float16*)nullptr, progA, Tlen);

    // 3) decoder phase: decL0 (producer, zero input, init enc finals) ||
    //    decL1 (consumer, init enc finals, writes final y to Y)
    lstm_fused2<false, true, true, true><<<dim3(32), dim3(512), 0, stream>>>(
        dU0, db0i, db0h, (const _Float16*)nullptr, fh0, fc0, fh0, fc0,
        dW1, dU1, db1i, db1h, fh1, fc1, fh1, fc1,
        XP /*publish scratch*/, Y, progB, Tlen);

    // 4) out = d1 @ out_W^T + out_b (f32 -> d_out, overwrites prog scratch)
    gemm_k128<true, false, true><<<gOut, blk, 0, stream>>>((const void*)Y, oW, ob, d_out, Mrows, Hd);
}